// Round 3
// baseline (2379.106 us; speedup 1.0000x reference)
//
#include <hip/hip_runtime.h>
#include <math.h>

// ---------------------------------------------------------------------------
// AttentionRoutingDetector — fp32 baseline; router decision emulates the np
// float32 pipeline with correctly-rounded ops.
// Evidence (R1 vs R2): np ref resolves the router mask in FLOAT32. Its fp32
// quantization is ground truth: scores quantize to 0.5 + k*2^-24; the outer
// sigmoid maps k<=1 -> hard=0 (1+(1-t) ties-to-even gives exactly 2.0 at k=1),
// k>=2 -> hard=1. We compute logit in fp64 (closest to np's fp32 value), then
// run the sigmoid chain in fp32 with correctly-rounded exp (double exp ->
// round) and IEEE add/div, reproducing np's table.
// ---------------------------------------------------------------------------

#define B_ALL 32

// ---------------- conv1: (b,3,512,512) -> relu -> (b,64,256,256), stride 2, SAME (pad lo=0 hi=1)
__global__ __launch_bounds__(256) void conv1_kernel(
    const float* __restrict__ img, const float* __restrict__ w,
    const float* __restrict__ bias, float* __restrict__ x1, int b0)
{
    const int ow = threadIdx.x;       // 0..255
    const int oh = blockIdx.x;        // 0..255
    const int bl = blockIdx.y;        // slice-local image
    const int b  = b0 + bl;

    const float* ib = img + (size_t)b * 3 * 512 * 512;
    float in[3][3][3];
#pragma unroll
    for (int c = 0; c < 3; c++)
#pragma unroll
        for (int kh = 0; kh < 3; kh++) {
            int ih = oh * 2 + kh;
#pragma unroll
            for (int kw = 0; kw < 3; kw++) {
                int iw = ow * 2 + kw;
                in[c][kh][kw] = (ih < 512 && iw < 512)
                    ? ib[((size_t)c * 512 + ih) * 512 + iw] : 0.f;
            }
        }

    float* ob = x1 + ((size_t)bl * 64 * 256 + oh) * 256 + ow;
#pragma unroll 2
    for (int oc = 0; oc < 64; oc++) {
        const float* wp = w + oc * 27;        // uniform -> s_load
        float p[3] = {0.f, 0.f, 0.f};         // per-input-channel partials
#pragma unroll
        for (int c = 0; c < 3; c++)
#pragma unroll
            for (int kh = 0; kh < 3; kh++)
#pragma unroll
                for (int kw = 0; kw < 3; kw++)
                    p[c] = fmaf(in[c][kh][kw], wp[(c * 3 + kh) * 3 + kw], p[c]);
        double s = (double)bias[oc] + ((double)p[0] + (double)p[1] + (double)p[2]);
        float r = (float)s;
        ob[(size_t)oc * 256 * 256] = r > 0.f ? r : 0.f;
    }
}

// ---------------- conv2: (bl,64,256,256) -> relu -> (bl,64,128,128), stride 2, SAME (pad lo=0 hi=1)
// block: 256 thr = 32 owg x 8 ocg; each thread: 4 ow x 8 oc accumulators.
// fp32 FMA within each 8-ic block (72 terms), carried into fp64 accumulators.
__global__ __launch_bounds__(256) void conv2_kernel(
    const float* __restrict__ x1, const float* __restrict__ w,
    const float* __restrict__ bias, float* __restrict__ x2)
{
    __shared__ float in_lds[8][3][2][132];   // [ic][kh][parity][half-col]
    __shared__ float w_lds[72][64];          // [ic*9+kh*3+kw][oc]

    const int tid = threadIdx.x;
    const int owg = tid & 31;
    const int ocg = tid >> 5;
    const int oh  = blockIdx.x;              // 0..127
    const int bl  = blockIdx.y;

    const float* xb = x1 + (size_t)bl * 64 * 256 * 256;

    float acc[4][8];
    double accd[4][8];
#pragma unroll
    for (int j = 0; j < 4; j++)
#pragma unroll
        for (int o = 0; o < 8; o++) { acc[j][o] = 0.f; accd[j][o] = 0.0; }

    for (int ic0 = 0; ic0 < 64; ic0 += 8) {
        // stage inputs: 8 ic x 3 kh x 257 iw
        for (int idx = tid; idx < 8 * 3 * 257; idx += 256) {
            int ic = idx / 771;
            int rem = idx - ic * 771;
            int kh = rem / 257;
            int iw = rem - kh * 257;
            int ih = oh * 2 + kh;
            float v = 0.f;
            if (ih < 256 && iw < 256)
                v = xb[((size_t)(ic0 + ic) * 256 + ih) * 256 + iw];
            in_lds[ic][kh][iw & 1][iw >> 1] = v;
        }
        // stage weights: w layout (oc,ic,kh,kw)
        for (int idx = tid; idx < 72 * 64; idx += 256) {
            int r = idx >> 6;
            int oc = idx & 63;
            int ic = r / 9;
            int q  = r - ic * 9;
            w_lds[r][oc] = w[(size_t)oc * 576 + (ic0 + ic) * 9 + q];
        }
        __syncthreads();

        for (int ic = 0; ic < 8; ic++) {
#pragma unroll
            for (int kh = 0; kh < 3; kh++) {
                const float* ebase = &in_lds[ic][kh][0][0];
                const float* obase = &in_lds[ic][kh][1][0];
                float4 e0 = *(const float4*)(ebase + owg * 4);
                float  e4 = ebase[owg * 4 + 4];
                float4 o0 = *(const float4*)(obase + owg * 4);
                float iv[3][4];
                iv[0][0] = e0.x; iv[0][1] = e0.y; iv[0][2] = e0.z; iv[0][3] = e0.w;
                iv[1][0] = o0.x; iv[1][1] = o0.y; iv[1][2] = o0.z; iv[1][3] = o0.w;
                iv[2][0] = e0.y; iv[2][1] = e0.z; iv[2][2] = e0.w; iv[2][3] = e4;
                const float* wr = &w_lds[ic * 9 + kh * 3][0];
#pragma unroll
                for (int kw = 0; kw < 3; kw++) {
                    float4 w0 = *(const float4*)(wr + kw * 64 + ocg * 8);
                    float4 w1 = *(const float4*)(wr + kw * 64 + ocg * 8 + 4);
                    float wv[8] = {w0.x, w0.y, w0.z, w0.w, w1.x, w1.y, w1.z, w1.w};
#pragma unroll
                    for (int j = 0; j < 4; j++) {
                        float a = iv[kw][j];
#pragma unroll
                        for (int o = 0; o < 8; o++)
                            acc[j][o] = fmaf(a, wv[o], acc[j][o]);
                    }
                }
            }
        }
        // carry this 72-term fp32 partial into fp64
#pragma unroll
        for (int j = 0; j < 4; j++)
#pragma unroll
            for (int o = 0; o < 8; o++) {
                accd[j][o] += (double)acc[j][o];
                acc[j][o] = 0.f;
            }
        __syncthreads();
    }

#pragma unroll
    for (int o = 0; o < 8; o++) {
        int oc = ocg * 8 + o;
        double bv = (double)bias[oc];
        float4 v;
        v.x = fmaxf((float)(accd[0][o] + bv), 0.f);
        v.y = fmaxf((float)(accd[1][o] + bv), 0.f);
        v.z = fmaxf((float)(accd[2][o] + bv), 0.f);
        v.w = fmaxf((float)(accd[3][o] + bv), 0.f);
        *(float4*)&x2[(((size_t)bl * 64 + oc) * 128 + oh) * 128 + owg * 4] = v;
    }
}

// ---------------- pool (8x8 mean) + attention MLP (64->32->1)
// logit in fp64, then fp32-quantized sigmoid chain emulating np float32:
//   e1 = rnd32(exp(-lf)); d1 = 1f+e1; s = rnd32(1/d1)    [scores]
//   t = s - thr; e2 = rnd32(exp(-t)); soft = rnd32(1/(1f+e2)); hard = soft>0.5f
__global__ __launch_bounds__(64) void pool_attn_kernel(
    const float* __restrict__ x2, const float* __restrict__ aw1,
    const float* __restrict__ ab1, const float* __restrict__ aw2,
    const float* __restrict__ ab2, const float* __restrict__ thrp,
    float* __restrict__ scores, float* __restrict__ maskf, int b0)
{
    const int c  = threadIdx.x;   // channel 0..63
    const int n  = blockIdx.x;    // patch 0..255
    const int bl = blockIdx.y;
    const int i = n >> 4, j = n & 15;

    const float* xp = x2 + (((size_t)bl * 64 + c) * 128 + i * 8) * 128 + j * 8;
    double s = 0.0;
#pragma unroll
    for (int p = 0; p < 8; p++) {
        float4 a = *(const float4*)&xp[p * 128];
        float4 b = *(const float4*)&xp[p * 128 + 4];
        s += (double)a.x + (double)a.y + (double)a.z + (double)a.w
           + (double)b.x + (double)b.y + (double)b.z + (double)b.w;
    }
    __shared__ double tok[64];
    __shared__ double h[32];
    tok[c] = s * (1.0 / 64.0);
    __syncthreads();
    if (c < 32) {
        double acc = (double)ab1[c];
        for (int k = 0; k < 64; k++) acc += tok[k] * (double)aw1[k * 32 + c];
        h[c] = acc > 0.0 ? acc : 0.0;
    }
    __syncthreads();
    if (c == 0) {
        double logit = (double)ab2[0];
        for (int k = 0; k < 32; k++) logit += h[k] * (double)aw2[k];
        // ---- fp32 emulation of np's sigmoid chain (correctly-rounded ops)
        float lf = (float)logit;
        float e1 = (float)exp(-(double)lf);      // CR fp32 exp
        float d1 = 1.0f + e1;                    // IEEE fp32 add
        float sc = (float)(1.0 / (double)d1);    // CR fp32 div
        float t  = sc - thrp[0];                 // exact (both near 0.5)
        float e2 = (float)exp(-(double)t);       // = 1 - t exactly in this range
        float d2 = 1.0f + e2;                    // ties-to-even: k=1 -> 2.0
        float soft = (float)(1.0 / (double)d2);
        scores[(size_t)(b0 + bl) * 256 + n] = sc;
        maskf[(size_t)(b0 + bl) * 256 + n] = (soft > 0.5f) ? 1.f : 0.f;
    }
}

// ---------------- per-batch score sum (for attn_pool normalization)
__global__ __launch_bounds__(256) void wsum_kernel(
    const float* __restrict__ scores, float* __restrict__ wsum)
{
    int b = blockIdx.x, t = threadIdx.x;
    float v = scores[b * 256 + t];
#pragma unroll
    for (int o = 32; o > 0; o >>= 1) v += __shfl_down(v, o);
    __shared__ float ls[4];
    if ((t & 63) == 0) ls[t >> 6] = v;
    __syncthreads();
    if (t == 0) wsum[b] = (ls[0] + ls[1] + ls[2] + ls[3]) + 1e-6f;
}

// ---------------- generic fp32 GEMM: C = epi(A @ W + bias)
// 64x64 tile, BK=32, 256 thr, 4x4 microtile.
// AMODE 0: A given. AMODE 1: A[m][k] = k<256 ? g[b][k] : comb[m][k-256]
// EPI 0: relu->C | 1: ->C | 2: write C only where mask==1 | 3: only where mask==0
template <int AMODE, int EPI>
__global__ __launch_bounds__(256) void gemm_kernel(
    const float* __restrict__ A, const float* __restrict__ W,
    const float* __restrict__ bias, float* __restrict__ C,
    int M, int N, int K,
    const float* __restrict__ g, const float* __restrict__ comb,
    const float* __restrict__ maskf)
{
    __shared__ float As[32][68];
    __shared__ float Ws[32][68];

    const int tid = threadIdx.x;
    const int n0 = blockIdx.x * 64;
    const int m0 = blockIdx.y * 64;
    const int tx = tid & 15, ty = tid >> 4;

    const int la_m = tid >> 2;
    const int la_k = (tid & 3) * 4;
    const int lw_k = tid >> 4;
    const int lw_n = (tid & 15) * 4;

    float acc[4][4];
#pragma unroll
    for (int i = 0; i < 4; i++)
#pragma unroll
        for (int j = 0; j < 4; j++) acc[i][j] = 0.f;

    for (int k0 = 0; k0 < K; k0 += 32) {
        // ---- stage A (two k-halves)
#pragma unroll
        for (int half = 0; half < 2; half++) {
            int kk = la_k + half * 16;
            if (AMODE == 0) {
                float4 av = *(const float4*)&A[(size_t)(m0 + la_m) * K + k0 + kk];
                As[kk + 0][la_m] = av.x;
                As[kk + 1][la_m] = av.y;
                As[kk + 2][la_m] = av.z;
                As[kk + 3][la_m] = av.w;
            } else {
                int m = m0 + la_m;
                int bb = m >> 8;
#pragma unroll
                for (int q = 0; q < 4; q++) {
                    int k = k0 + kk + q;
                    float v = (k < 256) ? g[bb * 256 + k]
                                        : comb[(size_t)m * 128 + (k - 256)];
                    As[kk + q][la_m] = v;
                }
            }
        }
        // ---- stage W (two k-halves)
#pragma unroll
        for (int half = 0; half < 2; half++) {
            int kk = lw_k + half * 16;
            *(float4*)&Ws[kk][lw_n] =
                *(const float4*)&W[(size_t)(k0 + kk) * N + n0 + lw_n];
        }
        __syncthreads();
#pragma unroll
        for (int k = 0; k < 32; k++) {
            float4 a4 = *(const float4*)&As[k][ty * 4];
            float4 w4 = *(const float4*)&Ws[k][tx * 4];
            acc[0][0] = fmaf(a4.x, w4.x, acc[0][0]);
            acc[0][1] = fmaf(a4.x, w4.y, acc[0][1]);
            acc[0][2] = fmaf(a4.x, w4.z, acc[0][2]);
            acc[0][3] = fmaf(a4.x, w4.w, acc[0][3]);
            acc[1][0] = fmaf(a4.y, w4.x, acc[1][0]);
            acc[1][1] = fmaf(a4.y, w4.y, acc[1][1]);
            acc[1][2] = fmaf(a4.y, w4.z, acc[1][2]);
            acc[1][3] = fmaf(a4.y, w4.w, acc[1][3]);
            acc[2][0] = fmaf(a4.z, w4.x, acc[2][0]);
            acc[2][1] = fmaf(a4.z, w4.y, acc[2][1]);
            acc[2][2] = fmaf(a4.z, w4.z, acc[2][2]);
            acc[2][3] = fmaf(a4.z, w4.w, acc[2][3]);
            acc[3][0] = fmaf(a4.w, w4.x, acc[3][0]);
            acc[3][1] = fmaf(a4.w, w4.y, acc[3][1]);
            acc[3][2] = fmaf(a4.w, w4.z, acc[3][2]);
            acc[3][3] = fmaf(a4.w, w4.w, acc[3][3]);
        }
        __syncthreads();
    }

    float4 bv = *(const float4*)&bias[n0 + tx * 4];
#pragma unroll
    for (int i = 0; i < 4; i++) {
        int m = m0 + ty * 4 + i;
        float4 v;
        v.x = acc[i][0] + bv.x;
        v.y = acc[i][1] + bv.y;
        v.z = acc[i][2] + bv.z;
        v.w = acc[i][3] + bv.w;
        if (EPI == 0) {
            v.x = fmaxf(v.x, 0.f); v.y = fmaxf(v.y, 0.f);
            v.z = fmaxf(v.z, 0.f); v.w = fmaxf(v.w, 0.f);
        }
        bool do_store = true;
        if (EPI == 2) do_store = (maskf[m] > 0.5f);
        if (EPI == 3) do_store = (maskf[m] < 0.5f);
        if (do_store)
            *(float4*)&C[(size_t)m * N + n0 + tx * 4] = v;
    }
}

// ---------------- per-batch pooling of comb: mean & score-weighted
__global__ __launch_bounds__(128) void pool2_kernel(
    const float* __restrict__ comb, const float* __restrict__ scores,
    const float* __restrict__ wsum, float* __restrict__ meanp,
    float* __restrict__ attnp)
{
    int b = blockIdx.x, d = threadIdx.x;
    float ms = 0.f, as = 0.f;
    for (int n = 0; n < 256; n++) {
        float v = comb[((size_t)b * 256 + n) * 128 + d];
        ms += v;
        as = fmaf(scores[b * 256 + n], v, as);
    }
    meanp[b * 128 + d] = ms * (1.f / 256.f);
    attnp[b * 128 + d] = as / wsum[b];
}

// ---------------- aggregator: g = relu(concat(meanp, attnp) @ gw + gb)
__global__ __launch_bounds__(256) void agg_kernel(
    const float* __restrict__ meanp, const float* __restrict__ attnp,
    const float* __restrict__ gw, const float* __restrict__ gb,
    float* __restrict__ g)
{
    int b = blockIdx.x, j = threadIdx.x;
    __shared__ float cat[256];
    cat[j] = (j < 128) ? meanp[b * 128 + j] : attnp[b * 128 + j - 128];
    __syncthreads();
    float acc = gb[j];
    for (int k = 0; k < 256; k++) acc = fmaf(cat[k], gw[k * 256 + j], acc);
    g[b * 256 + j] = acc > 0.f ? acc : 0.f;
}

// ---------------- detection heads: cls = hd@cls_w+b, reg = hd@reg_w+b
__global__ __launch_bounds__(128) void det2_kernel(
    const float* __restrict__ hd, const float* __restrict__ cls_w,
    const float* __restrict__ cls_b, const float* __restrict__ reg_w,
    const float* __restrict__ reg_b, float* __restrict__ out)
{
    int m = blockIdx.x;   // 0..8191
    int t = threadIdx.x;  // 0..127
    __shared__ float row[256];
    row[t] = hd[(size_t)m * 256 + t];
    row[t + 128] = hd[(size_t)m * 256 + t + 128];
    __syncthreads();
    if (t < 80) {
        float acc = cls_b[t];
        for (int k = 0; k < 256; k++) acc = fmaf(row[k], cls_w[k * 80 + t], acc);
        out[(size_t)m * 80 + t] = acc;
    } else if (t < 84) {
        int j = t - 80;
        float acc = reg_b[j];
        for (int k = 0; k < 256; k++) acc = fmaf(row[k], reg_w[k * 4 + j], acc);
        out[655360 + (size_t)m * 4 + j] = acc;
    }
}

// ---------------------------------------------------------------------------
extern "C" void kernel_launch(void* const* d_in, const int* in_sizes, int n_in,
                              void* d_out, int out_size, void* d_ws, size_t ws_size,
                              hipStream_t stream)
{
    (void)in_sizes; (void)n_in; (void)out_size;

    const float* images = (const float*)d_in[0];
    const float* patches = (const float*)d_in[1];
    const float* cw1 = (const float*)d_in[2];
    const float* cb1 = (const float*)d_in[3];
    const float* cw2 = (const float*)d_in[4];
    const float* cb2 = (const float*)d_in[5];
    const float* aw1 = (const float*)d_in[6];
    const float* ab1 = (const float*)d_in[7];
    const float* aw2 = (const float*)d_in[8];
    const float* ab2 = (const float*)d_in[9];
    const float* thr = (const float*)d_in[10];
    const float* bw1 = (const float*)d_in[11];
    const float* bb1 = (const float*)d_in[12];
    const float* bw2 = (const float*)d_in[13];
    const float* bb2 = (const float*)d_in[14];
    const float* bw3 = (const float*)d_in[15];
    const float* bb3 = (const float*)d_in[16];
    const float* bw4 = (const float*)d_in[17];
    const float* bb4 = (const float*)d_in[18];
    const float* sw1 = (const float*)d_in[19];
    const float* sb1 = (const float*)d_in[20];
    const float* sw2 = (const float*)d_in[21];
    const float* sb2 = (const float*)d_in[22];
    const float* gw  = (const float*)d_in[23];
    const float* gb  = (const float*)d_in[24];
    const float* dw1 = (const float*)d_in[25];
    const float* db1 = (const float*)d_in[26];
    const float* cls_w = (const float*)d_in[27];
    const float* cls_b = (const float*)d_in[28];
    const float* reg_w = (const float*)d_in[29];
    const float* reg_b = (const float*)d_in[30];
    float* out = (float*)d_out;

    // pick largest backbone batch-slice that fits the workspace
    const size_t fixed = 8192 + 8192 + 32 + 2 * 4194304ull + 524288 + 1048576
                       + 4096 + 4096 + 8192 + 2097152;
    int SL = 8;
    while (SL > 1) {
        size_t need = ((size_t)SL * 64 * 256 * 256 + (size_t)SL * 64 * 128 * 128 + fixed) * 4;
        if (need <= ws_size) break;
        SL >>= 1;
    }

    float* ws = (float*)d_ws;
    float* x1     = ws;
    float* x2s    = x1 + (size_t)SL * 64 * 256 * 256;
    float* scores = x2s + (size_t)SL * 64 * 128 * 128;
    float* maskf  = scores + 8192;
    float* wsum   = maskf + 8192;
    float* hb1    = wsum + 32;
    float* hb2    = hb1 + 4194304;
    float* hs     = hb2 + 4194304;
    float* comb   = hs + 524288;
    float* meanp  = comb + 1048576;
    float* attnp  = meanp + 4096;
    float* g      = attnp + 4096;
    float* hd     = g + 8192;

    // backbone + attention scores, batch-sliced
    for (int s = 0; s < B_ALL / SL; s++) {
        conv1_kernel<<<dim3(256, SL), 256, 0, stream>>>(images, cw1, cb1, x1, s * SL);
        conv2_kernel<<<dim3(128, SL), 256, 0, stream>>>(x1, cw2, cb2, x2s);
        pool_attn_kernel<<<dim3(256, SL), 64, 0, stream>>>(x2s, aw1, ab1, aw2, ab2,
                                                           thr, scores, maskf, s * SL);
    }
    wsum_kernel<<<32, 256, 0, stream>>>(scores, wsum);

    // experts (dense), mask-select write into comb
    gemm_kernel<0, 0><<<dim3(8, 128), 256, 0, stream>>>(patches, bw1, bb1, hb1,
        8192, 512, 3072, nullptr, nullptr, nullptr);
    gemm_kernel<0, 0><<<dim3(8, 128), 256, 0, stream>>>(hb1, bw2, bb2, hb2,
        8192, 512, 512, nullptr, nullptr, nullptr);
    gemm_kernel<0, 0><<<dim3(8, 128), 256, 0, stream>>>(hb2, bw3, bb3, hb1,
        8192, 512, 512, nullptr, nullptr, nullptr);
    gemm_kernel<0, 2><<<dim3(2, 128), 256, 0, stream>>>(hb1, bw4, bb4, comb,
        8192, 128, 512, nullptr, nullptr, maskf);
    gemm_kernel<0, 0><<<dim3(1, 128), 256, 0, stream>>>(patches, sw1, sb1, hs,
        8192, 64, 3072, nullptr, nullptr, nullptr);
    gemm_kernel<0, 3><<<dim3(2, 128), 256, 0, stream>>>(hs, sw2, sb2, comb,
        8192, 128, 64, nullptr, nullptr, maskf);

    // aggregate + detection
    pool2_kernel<<<32, 128, 0, stream>>>(comb, scores, wsum, meanp, attnp);
    agg_kernel<<<32, 256, 0, stream>>>(meanp, attnp, gw, gb, g);
    gemm_kernel<1, 0><<<dim3(4, 128), 256, 0, stream>>>(nullptr, dw1, db1, hd,
        8192, 256, 384, g, comb, nullptr);
    det2_kernel<<<8192, 128, 0, stream>>>(hd, cls_w, cls_b, reg_w, reg_b, out);
}

// Round 4
// 2120.369 us; speedup vs baseline: 1.1220x; 1.1220x over previous
//
#include <hip/hip_runtime.h>
#include <math.h>

// ---------------------------------------------------------------------------
// AttentionRoutingDetector — R4: split-bf16 MFMA experts + fused conv2/pool.
// Router path (conv1/conv2/pool/attn-MLP) stays fp32-with-fp64-carry and the
// fp32-emulated sigmoid chain (R3, verified). Expert/detection GEMMs move to
// MFMA bf16x3 (ah*wh + ah*wl + al*wh ~ fp32 accuracy, smooth path only).
// x2 is never materialized: conv2 pools 8x8 blocks in-kernel -> tokd (fp64).
// ---------------------------------------------------------------------------

#define B_ALL 32

typedef __attribute__((ext_vector_type(8))) short short8;
typedef __attribute__((ext_vector_type(4))) float f32x4;

__device__ __forceinline__ unsigned short f2bf(float x) {
    unsigned u = __float_as_uint(x);
    return (unsigned short)((u + 0x7FFFu + ((u >> 16) & 1u)) >> 16);
}
__device__ __forceinline__ float bf2f(unsigned short h) {
    return __uint_as_float(((unsigned)h) << 16);
}
__device__ __forceinline__ unsigned pk(unsigned short a, unsigned short b) {
    return (unsigned)a | ((unsigned)b << 16);
}

// ---------------- conv1: (b,3,512,512) -> relu -> (b,64,256,256), stride 2
__global__ __launch_bounds__(256) void conv1_kernel(
    const float* __restrict__ img, const float* __restrict__ w,
    const float* __restrict__ bias, float* __restrict__ x1, int b0)
{
    const int ow = threadIdx.x;
    const int oh = blockIdx.x;
    const int bl = blockIdx.y;
    const int b  = b0 + bl;

    const float* ib = img + (size_t)b * 3 * 512 * 512;
    float in[3][3][3];
#pragma unroll
    for (int c = 0; c < 3; c++)
#pragma unroll
        for (int kh = 0; kh < 3; kh++) {
            int ih = oh * 2 + kh;
#pragma unroll
            for (int kw = 0; kw < 3; kw++) {
                int iw = ow * 2 + kw;
                in[c][kh][kw] = (ih < 512 && iw < 512)
                    ? ib[((size_t)c * 512 + ih) * 512 + iw] : 0.f;
            }
        }

    float* ob = x1 + ((size_t)bl * 64 * 256 + oh) * 256 + ow;
#pragma unroll 2
    for (int oc = 0; oc < 64; oc++) {
        const float* wp = w + oc * 27;
        float p[3] = {0.f, 0.f, 0.f};
#pragma unroll
        for (int c = 0; c < 3; c++)
#pragma unroll
            for (int kh = 0; kh < 3; kh++)
#pragma unroll
                for (int kw = 0; kw < 3; kw++)
                    p[c] = fmaf(in[c][kh][kw], wp[(c * 3 + kh) * 3 + kw], p[c]);
        double s = (double)bias[oc] + ((double)p[0] + (double)p[1] + (double)p[2]);
        float r = (float)s;
        ob[(size_t)oc * 256 * 256] = r > 0.f ? r : 0.f;
    }
}

// ---------------- conv2 + fused 8x8 pool partials.
// Per block: one oh row of conv2 (bl, all 64 oc, 128 ow), fp64-carried fp32.
// Writes tokd partials [bl][oc][oh][j] (sum over the 8 ow of pool-col j).
__global__ __launch_bounds__(256) void conv2_kernel(
    const float* __restrict__ x1, const float* __restrict__ w,
    const float* __restrict__ bias, double* __restrict__ tokd)
{
    __shared__ float in_lds[8][3][2][132];
    __shared__ float w_lds[72][64];

    const int tid = threadIdx.x;
    const int owg = tid & 31;
    const int ocg = tid >> 5;
    const int oh  = blockIdx.x;
    const int bl  = blockIdx.y;

    const float* xb = x1 + (size_t)bl * 64 * 256 * 256;

    float acc[4][8];
    double accd[4][8];
#pragma unroll
    for (int j = 0; j < 4; j++)
#pragma unroll
        for (int o = 0; o < 8; o++) { acc[j][o] = 0.f; accd[j][o] = 0.0; }

    for (int ic0 = 0; ic0 < 64; ic0 += 8) {
        for (int idx = tid; idx < 8 * 3 * 257; idx += 256) {
            int ic = idx / 771;
            int rem = idx - ic * 771;
            int kh = rem / 257;
            int iw = rem - kh * 257;
            int ih = oh * 2 + kh;
            float v = 0.f;
            if (ih < 256 && iw < 256)
                v = xb[((size_t)(ic0 + ic) * 256 + ih) * 256 + iw];
            in_lds[ic][kh][iw & 1][iw >> 1] = v;
        }
        for (int idx = tid; idx < 72 * 64; idx += 256) {
            int r = idx >> 6;
            int oc = idx & 63;
            int ic = r / 9;
            int q  = r - ic * 9;
            w_lds[r][oc] = w[(size_t)oc * 576 + (ic0 + ic) * 9 + q];
        }
        __syncthreads();

        for (int ic = 0; ic < 8; ic++) {
#pragma unroll
            for (int kh = 0; kh < 3; kh++) {
                const float* ebase = &in_lds[ic][kh][0][0];
                const float* obase = &in_lds[ic][kh][1][0];
                float4 e0 = *(const float4*)(ebase + owg * 4);
                float  e4 = ebase[owg * 4 + 4];
                float4 o0 = *(const float4*)(obase + owg * 4);
                float iv[3][4];
                iv[0][0] = e0.x; iv[0][1] = e0.y; iv[0][2] = e0.z; iv[0][3] = e0.w;
                iv[1][0] = o0.x; iv[1][1] = o0.y; iv[1][2] = o0.z; iv[1][3] = o0.w;
                iv[2][0] = e0.y; iv[2][1] = e0.z; iv[2][2] = e0.w; iv[2][3] = e4;
                const float* wr = &w_lds[ic * 9 + kh * 3][0];
#pragma unroll
                for (int kw = 0; kw < 3; kw++) {
                    float4 w0 = *(const float4*)(wr + kw * 64 + ocg * 8);
                    float4 w1 = *(const float4*)(wr + kw * 64 + ocg * 8 + 4);
                    float wv[8] = {w0.x, w0.y, w0.z, w0.w, w1.x, w1.y, w1.z, w1.w};
#pragma unroll
                    for (int j = 0; j < 4; j++) {
                        float a = iv[kw][j];
#pragma unroll
                        for (int o = 0; o < 8; o++)
                            acc[j][o] = fmaf(a, wv[o], acc[j][o]);
                    }
                }
            }
        }
#pragma unroll
        for (int j = 0; j < 4; j++)
#pragma unroll
            for (int o = 0; o < 8; o++) {
                accd[j][o] += (double)acc[j][o];
                acc[j][o] = 0.f;
            }
        __syncthreads();
    }

    // fused pool: relu(fp32-rounded) then pair-reduce 8 ow per pool col
#pragma unroll
    for (int o = 0; o < 8; o++) {
        int oc = ocg * 8 + o;
        double bv = (double)bias[oc];
        double sdp = 0.0;
#pragma unroll
        for (int j4 = 0; j4 < 4; j4++)
            sdp += (double)fmaxf((float)(accd[j4][o] + bv), 0.f);
        sdp += __shfl_xor(sdp, 1);
        if ((owg & 1) == 0)
            tokd[(((size_t)bl * 64 + oc) * 128 + oh) * 16 + (owg >> 1)] = sdp;
    }
}

// ---------------- attention MLP from pooled tokens (fp64) + fp32-emulated
// sigmoid chain (identical to R3's verified decision rule).
__global__ __launch_bounds__(64) void attn_kernel(
    const double* __restrict__ tokd, const float* __restrict__ aw1,
    const float* __restrict__ ab1, const float* __restrict__ aw2,
    const float* __restrict__ ab2, const float* __restrict__ thrp,
    float* __restrict__ scores, float* __restrict__ maskf, int b0)
{
    const int c  = threadIdx.x;
    const int n  = blockIdx.x;
    const int bl = blockIdx.y;
    const int i = n >> 4, j = n & 15;

    const double* tp = tokd + (((size_t)bl * 64 + c) * 128 + i * 8) * 16 + j;
    double s = 0.0;
#pragma unroll
    for (int p = 0; p < 8; p++) s += tp[p * 16];

    __shared__ double tok[64];
    __shared__ double h[32];
    tok[c] = s * (1.0 / 64.0);
    __syncthreads();
    if (c < 32) {
        double acc = (double)ab1[c];
        for (int k = 0; k < 64; k++) acc += tok[k] * (double)aw1[k * 32 + c];
        h[c] = acc > 0.0 ? acc : 0.0;
    }
    __syncthreads();
    if (c == 0) {
        double logit = (double)ab2[0];
        for (int k = 0; k < 32; k++) logit += h[k] * (double)aw2[k];
        float lf = (float)logit;
        float e1 = (float)exp(-(double)lf);
        float d1 = 1.0f + e1;
        float sc = (float)(1.0 / (double)d1);
        float t  = sc - thrp[0];
        float e2 = (float)exp(-(double)t);
        float d2 = 1.0f + e2;
        float soft = (float)(1.0 / (double)d2);
        scores[(size_t)(b0 + bl) * 256 + n] = sc;
        maskf[(size_t)(b0 + bl) * 256 + n] = (soft > 0.5f) ? 1.f : 0.f;
    }
}

// ---------------- per-batch score sum
__global__ __launch_bounds__(256) void wsum_kernel(
    const float* __restrict__ scores, float* __restrict__ wsum)
{
    int b = blockIdx.x, t = threadIdx.x;
    float v = scores[b * 256 + t];
#pragma unroll
    for (int o = 32; o > 0; o >>= 1) v += __shfl_down(v, o);
    __shared__ float ls[4];
    if ((t & 63) == 0) ls[t >> 6] = v;
    __syncthreads();
    if (t == 0) wsum[b] = (ls[0] + ls[1] + ls[2] + ls[3]) + 1e-6f;
}

// ---------------- weight prep: pack W (KxN fp32) into MFMA fragment layout,
// split bf16 hi/lo: Wp[nt][kt][sub][h][lane][8]
__global__ __launch_bounds__(256) void wprep(
    const float* __restrict__ W, unsigned short* __restrict__ Wp, int K, int N, int Npad)
{
    int idx = blockIdx.x * 256 + threadIdx.x;
    int KT = K >> 5;
    int total = (Npad >> 6) * KT * 4 * 64;
    if (idx >= total) return;
    int lane = idx & 63;
    int sub  = (idx >> 6) & 3;
    int t    = idx >> 8;
    int kt = t % KT, nt = t / KT;
    int n  = nt * 64 + sub * 16 + (lane & 15);
    int k0 = kt * 32 + (lane >> 4) * 8;
    unsigned hw[4], lw[4];
#pragma unroll
    for (int q = 0; q < 4; q++) {
        float x0 = (n < N) ? W[(size_t)(k0 + 2 * q) * N + n] : 0.f;
        float x1 = (n < N) ? W[(size_t)(k0 + 2 * q + 1) * N + n] : 0.f;
        unsigned short h0 = f2bf(x0), h1 = f2bf(x1);
        hw[q] = pk(h0, h1);
        lw[q] = pk(f2bf(x0 - bf2f(h0)), f2bf(x1 - bf2f(h1)));
    }
    size_t base = ((((size_t)(nt * KT + kt) * 4 + sub) * 2) * 64 + lane) * 8;
    *(uint4*)(Wp + base)       = make_uint4(hw[0], hw[1], hw[2], hw[3]);
    *(uint4*)(Wp + base + 512) = make_uint4(lw[0], lw[1], lw[2], lw[3]);
}

// det head weights: concat cls_w (256x80) | reg_w (256x4), pad to 128 cols
__global__ __launch_bounds__(256) void wprep_det(
    const float* __restrict__ Wc, const float* __restrict__ Wr,
    unsigned short* __restrict__ Wp)
{
    int idx = blockIdx.x * 256 + threadIdx.x;
    const int KT = 8;
    int total = 2 * KT * 4 * 64;
    if (idx >= total) return;
    int lane = idx & 63;
    int sub  = (idx >> 6) & 3;
    int t    = idx >> 8;
    int kt = t % KT, nt = t / KT;
    int n  = nt * 64 + sub * 16 + (lane & 15);
    int k0 = kt * 32 + (lane >> 4) * 8;
    unsigned hw[4], lw[4];
#pragma unroll
    for (int q = 0; q < 4; q++) {
        int ka = k0 + 2 * q, kb = k0 + 2 * q + 1;
        float x0 = (n < 80) ? Wc[(size_t)ka * 80 + n] : (n < 84 ? Wr[(size_t)ka * 4 + n - 80] : 0.f);
        float x1 = (n < 80) ? Wc[(size_t)kb * 80 + n] : (n < 84 ? Wr[(size_t)kb * 4 + n - 80] : 0.f);
        unsigned short h0 = f2bf(x0), h1 = f2bf(x1);
        hw[q] = pk(h0, h1);
        lw[q] = pk(f2bf(x0 - bf2f(h0)), f2bf(x1 - bf2f(h1)));
    }
    size_t base = ((((size_t)(nt * KT + kt) * 4 + sub) * 2) * 64 + lane) * 8;
    *(uint4*)(Wp + base)       = make_uint4(hw[0], hw[1], hw[2], hw[3]);
    *(uint4*)(Wp + base + 512) = make_uint4(lw[0], lw[1], lw[2], lw[3]);
}

// ---------------- split-bf16 MFMA GEMM: C = epi(A @ W + bias)
// Tile 128(M) x 64(N) x 32(K); 4 waves, each 32 rows x 64 cols (8 C-tiles).
// ASRC: 0 = fp32 A (convert in staging); 1 = pre-split A (Ahg/Alg bf16);
//       2 = concat: kt<8 -> g fp32 (row m>>8, width 256); kt>=8 -> comb split (width 128)
// ACT: 1 = relu. MASK: 0 none / 1 keep(mask==1) / 2 keep(mask==0).
// OUTF: bit0 fp32 C, bit1 split Ch/Cl. EPID: 1 = detection dual-store (N=128 padded, real 84).
template <int ASRC, int ACT, int MASK, int OUTF, int EPID>
__global__ __launch_bounds__(256) void mgemm(
    const float* __restrict__ Af, const unsigned short* __restrict__ Ahg,
    const unsigned short* __restrict__ Alg, const unsigned short* __restrict__ Wp,
    const float* __restrict__ bias, float* __restrict__ Cf,
    unsigned short* __restrict__ Ch, unsigned short* __restrict__ Cl,
    const float* __restrict__ maskf, int K, int N, int KT,
    float* __restrict__ o80, float* __restrict__ o4,
    const float* __restrict__ clsb, const float* __restrict__ regb)
{
    __shared__ unsigned short AhL[128 * 40];
    __shared__ unsigned short AlL[128 * 40];

    const int tid  = threadIdx.x;
    const int wave = tid >> 6, lane = tid & 63;
    const int quad = lane >> 4, l16 = lane & 15;
    const int m0   = blockIdx.y * 128;
    const int srow = tid >> 1, shalf = tid & 1;

    f32x4 acc[2][4];
#pragma unroll
    for (int a = 0; a < 2; a++)
#pragma unroll
        for (int b = 0; b < 4; b++) acc[a][b] = (f32x4){0.f, 0.f, 0.f, 0.f};

    const unsigned short* wb = Wp + ((size_t)blockIdx.x * KT * 4 * 2 * 64 + lane) * 8;

    for (int kt = 0; kt < KT; kt++) {
        // ---- stage A tile (128 x 32)
        {
            const int m  = m0 + srow;
            const int kb = kt * 32 + shalf * 16;
            const int lofs = srow * 40 + shalf * 16;
            bool conv_path;
            if (ASRC == 0) conv_path = true;
            else if (ASRC == 1) conv_path = false;
            else conv_path = (kt < 8);

            if (conv_path) {
                const float* ap = (ASRC == 2) ? (Af + (size_t)(m >> 8) * 256 + kb)
                                              : (Af + (size_t)m * K + kb);
                float4 x0 = *(const float4*)(ap + 0);
                float4 x1 = *(const float4*)(ap + 4);
                float4 x2 = *(const float4*)(ap + 8);
                float4 x3 = *(const float4*)(ap + 12);
                float xv[16] = {x0.x, x0.y, x0.z, x0.w, x1.x, x1.y, x1.z, x1.w,
                                x2.x, x2.y, x2.z, x2.w, x3.x, x3.y, x3.z, x3.w};
                unsigned hw[8], lw[8];
#pragma unroll
                for (int q = 0; q < 8; q++) {
                    unsigned short h0 = f2bf(xv[2 * q]), h1 = f2bf(xv[2 * q + 1]);
                    unsigned short l0 = f2bf(xv[2 * q] - bf2f(h0));
                    unsigned short l1 = f2bf(xv[2 * q + 1] - bf2f(h1));
                    hw[q] = pk(h0, h1);
                    lw[q] = pk(l0, l1);
                }
                *(uint4*)&AhL[lofs]     = make_uint4(hw[0], hw[1], hw[2], hw[3]);
                *(uint4*)&AhL[lofs + 8] = make_uint4(hw[4], hw[5], hw[6], hw[7]);
                *(uint4*)&AlL[lofs]     = make_uint4(lw[0], lw[1], lw[2], lw[3]);
                *(uint4*)&AlL[lofs + 8] = make_uint4(lw[4], lw[5], lw[6], lw[7]);
            } else {
                const size_t ro = (ASRC == 2) ? ((size_t)m * 128 + (kb - 256))
                                              : ((size_t)m * K + kb);
                uint4 h0 = *(const uint4*)(Ahg + ro);
                uint4 h1 = *(const uint4*)(Ahg + ro + 8);
                uint4 l0 = *(const uint4*)(Alg + ro);
                uint4 l1 = *(const uint4*)(Alg + ro + 8);
                *(uint4*)&AhL[lofs]     = h0;
                *(uint4*)&AhL[lofs + 8] = h1;
                *(uint4*)&AlL[lofs]     = l0;
                *(uint4*)&AlL[lofs + 8] = l1;
            }
        }
        __syncthreads();

        const unsigned short* wk = wb + (size_t)kt * (4 * 2 * 64 * 8);
        short8 wh[4], wl[4];
#pragma unroll
        for (int s = 0; s < 4; s++) {
            wh[s] = *(const short8*)(wk + (size_t)s * (2 * 64 * 8));
            wl[s] = *(const short8*)(wk + (size_t)s * (2 * 64 * 8) + 64 * 8);
        }
        short8 ah[2], al[2];
#pragma unroll
        for (int mt = 0; mt < 2; mt++) {
            const int r = wave * 32 + mt * 16 + l16;
            ah[mt] = *(const short8*)&AhL[r * 40 + quad * 8];
            al[mt] = *(const short8*)&AlL[r * 40 + quad * 8];
        }
#pragma unroll
        for (int mt = 0; mt < 2; mt++)
#pragma unroll
            for (int s = 0; s < 4; s++) {
                acc[mt][s] = __builtin_amdgcn_mfma_f32_16x16x32_bf16(ah[mt], wh[s], acc[mt][s], 0, 0, 0);
                acc[mt][s] = __builtin_amdgcn_mfma_f32_16x16x32_bf16(al[mt], wh[s], acc[mt][s], 0, 0, 0);
                acc[mt][s] = __builtin_amdgcn_mfma_f32_16x16x32_bf16(ah[mt], wl[s], acc[mt][s], 0, 0, 0);
            }
        __syncthreads();
    }

    // ---- epilogue
    const int nbase = blockIdx.x * 64;
#pragma unroll
    for (int mt = 0; mt < 2; mt++) {
        const int mrow0 = m0 + wave * 32 + mt * 16 + quad * 4;
        float mk[4];
        if (MASK != 0) {
#pragma unroll
            for (int r = 0; r < 4; r++) mk[r] = maskf[mrow0 + r];
        }
#pragma unroll
        for (int s = 0; s < 4; s++) {
            const int n = nbase + s * 16 + l16;
            float bv;
            if (EPID == 1)
                bv = (n < 80) ? clsb[n] : (n < 84 ? regb[n - 80] : 0.f);
            else
                bv = bias[n];
#pragma unroll
            for (int r = 0; r < 4; r++) {
                const int m = mrow0 + r;
                float v = acc[mt][s][r] + bv;
                if (ACT) v = fmaxf(v, 0.f);
                bool st = true;
                if (MASK == 1) st = mk[r] > 0.5f;
                if (MASK == 2) st = mk[r] < 0.5f;
                if (st) {
                    if (OUTF & 1) Cf[(size_t)m * N + n] = v;
                    if (OUTF & 2) {
                        unsigned short hh = f2bf(v);
                        Ch[(size_t)m * N + n] = hh;
                        Cl[(size_t)m * N + n] = f2bf(v - bf2f(hh));
                    }
                    if (EPID == 1) {
                        if (n < 80)      o80[(size_t)m * 80 + n] = v;
                        else if (n < 84) o4[(size_t)m * 4 + (n - 80)] = v;
                    }
                }
            }
        }
    }
}

// ---------------- per-batch pooling of comb: mean & score-weighted
__global__ __launch_bounds__(128) void pool2_kernel(
    const float* __restrict__ comb, const float* __restrict__ scores,
    const float* __restrict__ wsum, float* __restrict__ meanp,
    float* __restrict__ attnp)
{
    int b = blockIdx.x, d = threadIdx.x;
    float ms = 0.f, as = 0.f;
    for (int n = 0; n < 256; n++) {
        float v = comb[((size_t)b * 256 + n) * 128 + d];
        ms += v;
        as = fmaf(scores[b * 256 + n], v, as);
    }
    meanp[b * 128 + d] = ms * (1.f / 256.f);
    attnp[b * 128 + d] = as / wsum[b];
}

// ---------------- aggregator
__global__ __launch_bounds__(256) void agg_kernel(
    const float* __restrict__ meanp, const float* __restrict__ attnp,
    const float* __restrict__ gw, const float* __restrict__ gb,
    float* __restrict__ g)
{
    int b = blockIdx.x, j = threadIdx.x;
    __shared__ float cat[256];
    cat[j] = (j < 128) ? meanp[b * 128 + j] : attnp[b * 128 + j - 128];
    __syncthreads();
    float acc = gb[j];
    for (int k = 0; k < 256; k++) acc = fmaf(cat[k], gw[k * 256 + j], acc);
    g[b * 256 + j] = acc > 0.f ? acc : 0.f;
}

// ---------------------------------------------------------------------------
extern "C" void kernel_launch(void* const* d_in, const int* in_sizes, int n_in,
                              void* d_out, int out_size, void* d_ws, size_t ws_size,
                              hipStream_t stream)
{
    (void)in_sizes; (void)n_in; (void)out_size;

    const float* images = (const float*)d_in[0];
    const float* patches = (const float*)d_in[1];
    const float* cw1 = (const float*)d_in[2];
    const float* cb1 = (const float*)d_in[3];
    const float* cw2 = (const float*)d_in[4];
    const float* cb2 = (const float*)d_in[5];
    const float* aw1 = (const float*)d_in[6];
    const float* ab1 = (const float*)d_in[7];
    const float* aw2 = (const float*)d_in[8];
    const float* ab2 = (const float*)d_in[9];
    const float* thr = (const float*)d_in[10];
    const float* bw1 = (const float*)d_in[11];
    const float* bb1 = (const float*)d_in[12];
    const float* bw2 = (const float*)d_in[13];
    const float* bb2 = (const float*)d_in[14];
    const float* bw3 = (const float*)d_in[15];
    const float* bb3 = (const float*)d_in[16];
    const float* bw4 = (const float*)d_in[17];
    const float* bb4 = (const float*)d_in[18];
    const float* sw1 = (const float*)d_in[19];
    const float* sb1 = (const float*)d_in[20];
    const float* sw2 = (const float*)d_in[21];
    const float* sb2 = (const float*)d_in[22];
    const float* gw  = (const float*)d_in[23];
    const float* gb  = (const float*)d_in[24];
    const float* dw1 = (const float*)d_in[25];
    const float* db1 = (const float*)d_in[26];
    const float* cls_w = (const float*)d_in[27];
    const float* cls_b = (const float*)d_in[28];
    const float* reg_w = (const float*)d_in[29];
    const float* reg_b = (const float*)d_in[30];
    float* out = (float*)d_out;
    float* o80 = out;
    float* o4  = out + 655360;

    // ---- workspace carve-up (bytes, 256-aligned)
    unsigned char* base = (unsigned char*)d_ws;
    size_t off = 0;
    auto alloc = [&](size_t bytes) -> unsigned char* {
        unsigned char* r = base + off;
        off += (bytes + 255) & ~(size_t)255;
        return r;
    };

    // fixed-size buffers first
    float*  scores = (float*)alloc(8192 * 4);
    float*  maskf  = (float*)alloc(8192 * 4);
    float*  wsumb  = (float*)alloc(32 * 4);
    float*  combf  = (float*)alloc((size_t)8192 * 128 * 4);
    float*  meanp  = (float*)alloc(4096 * 4);
    float*  attnp  = (float*)alloc(4096 * 4);
    float*  gbuf   = (float*)alloc(8192 * 4);

    typedef unsigned short ush;
    ush* wp_bw1 = (ush*)alloc((size_t)8 * 96 * 4096 * 2);
    ush* wp_bw2 = (ush*)alloc((size_t)8 * 16 * 4096 * 2);
    ush* wp_bw3 = (ush*)alloc((size_t)8 * 16 * 4096 * 2);
    ush* wp_bw4 = (ush*)alloc((size_t)2 * 16 * 4096 * 2);
    ush* wp_sw1 = (ush*)alloc((size_t)1 * 96 * 4096 * 2);
    ush* wp_sw2 = (ush*)alloc((size_t)2 * 2 * 4096 * 2);
    ush* wp_dw1 = (ush*)alloc((size_t)4 * 12 * 4096 * 2);
    ush* wp_det = (ush*)alloc((size_t)2 * 8 * 4096 * 2);

    ush* hb1h = (ush*)alloc((size_t)8192 * 512 * 2);
    ush* hb1l = (ush*)alloc((size_t)8192 * 512 * 2);
    ush* hb2h = (ush*)alloc((size_t)8192 * 512 * 2);
    ush* hb2l = (ush*)alloc((size_t)8192 * 512 * 2);
    ush* hb3h = (ush*)alloc((size_t)8192 * 512 * 2);
    ush* hb3l = (ush*)alloc((size_t)8192 * 512 * 2);
    ush* hsh  = (ush*)alloc((size_t)8192 * 64 * 2);
    ush* hsl  = (ush*)alloc((size_t)8192 * 64 * 2);
    ush* combh = (ush*)alloc((size_t)8192 * 128 * 2);
    ush* combl = (ush*)alloc((size_t)8192 * 128 * 2);
    ush* hdh  = (ush*)alloc((size_t)8192 * 256 * 2);
    ush* hdl  = (ush*)alloc((size_t)8192 * 256 * 2);

    // slice-sized buffers: x1 + tokd
    size_t remain = (ws_size > off) ? (ws_size - off) : 0;
    int SL = 8;
    while (SL > 1) {
        size_t need = (size_t)SL * 64 * 256 * 256 * 4 + (size_t)SL * 64 * 128 * 16 * 8 + 1024;
        if (need <= remain) break;
        SL >>= 1;
    }
    float*  x1   = (float*)alloc((size_t)SL * 64 * 256 * 256 * 4);
    double* tokd = (double*)alloc((size_t)SL * 64 * 128 * 16 * 8);

    // ---- weight preps
    {
        int t1 = 8 * 96 * 4 * 64;  wprep<<<(t1 + 255) / 256, 256, 0, stream>>>(bw1, wp_bw1, 3072, 512, 512);
        int t2 = 8 * 16 * 4 * 64;  wprep<<<(t2 + 255) / 256, 256, 0, stream>>>(bw2, wp_bw2, 512, 512, 512);
                                   wprep<<<(t2 + 255) / 256, 256, 0, stream>>>(bw3, wp_bw3, 512, 512, 512);
        int t4 = 2 * 16 * 4 * 64;  wprep<<<(t4 + 255) / 256, 256, 0, stream>>>(bw4, wp_bw4, 512, 128, 128);
        int t5 = 1 * 96 * 4 * 64;  wprep<<<(t5 + 255) / 256, 256, 0, stream>>>(sw1, wp_sw1, 3072, 64, 64);
        int t6 = 2 * 2 * 4 * 64;   wprep<<<(t6 + 255) / 256, 256, 0, stream>>>(sw2, wp_sw2, 64, 128, 128);
        int t7 = 4 * 12 * 4 * 64;  wprep<<<(t7 + 255) / 256, 256, 0, stream>>>(dw1, wp_dw1, 384, 256, 256);
        int t8 = 2 * 8 * 4 * 64;   wprep_det<<<(t8 + 255) / 256, 256, 0, stream>>>(cls_w, reg_w, wp_det);
    }

    // ---- backbone + attention scores, batch-sliced
    for (int s = 0; s < B_ALL / SL; s++) {
        conv1_kernel<<<dim3(256, SL), 256, 0, stream>>>(images, cw1, cb1, x1, s * SL);
        conv2_kernel<<<dim3(128, SL), 256, 0, stream>>>(x1, cw2, cb2, tokd);
        attn_kernel<<<dim3(256, SL), 64, 0, stream>>>(tokd, aw1, ab1, aw2, ab2,
                                                      thr, scores, maskf, s * SL);
    }
    wsum_kernel<<<32, 256, 0, stream>>>(scores, wsumb);

    // ---- experts (split-bf16 MFMA)
    mgemm<0, 1, 0, 2, 0><<<dim3(8, 64), 256, 0, stream>>>(
        patches, nullptr, nullptr, wp_bw1, bb1, nullptr, hb1h, hb1l, nullptr,
        3072, 512, 96, nullptr, nullptr, nullptr, nullptr);
    mgemm<1, 1, 0, 2, 0><<<dim3(8, 64), 256, 0, stream>>>(
        nullptr, hb1h, hb1l, wp_bw2, bb2, nullptr, hb2h, hb2l, nullptr,
        512, 512, 16, nullptr, nullptr, nullptr, nullptr);
    mgemm<1, 1, 0, 2, 0><<<dim3(8, 64), 256, 0, stream>>>(
        nullptr, hb2h, hb2l, wp_bw3, bb3, nullptr, hb3h, hb3l, nullptr,
        512, 512, 16, nullptr, nullptr, nullptr, nullptr);
    mgemm<1, 0, 1, 3, 0><<<dim3(2, 64), 256, 0, stream>>>(
        nullptr, hb3h, hb3l, wp_bw4, bb4, combf, combh, combl, maskf,
        512, 128, 16, nullptr, nullptr, nullptr, nullptr);
    mgemm<0, 1, 0, 2, 0><<<dim3(1, 64), 256, 0, stream>>>(
        patches, nullptr, nullptr, wp_sw1, sb1, nullptr, hsh, hsl, nullptr,
        3072, 64, 96, nullptr, nullptr, nullptr, nullptr);
    mgemm<1, 0, 2, 3, 0><<<dim3(2, 64), 256, 0, stream>>>(
        nullptr, hsh, hsl, wp_sw2, sb2, combf, combh, combl, maskf,
        64, 128, 2, nullptr, nullptr, nullptr, nullptr);

    // ---- aggregate + detection
    pool2_kernel<<<32, 128, 0, stream>>>(combf, scores, wsumb, meanp, attnp);
    agg_kernel<<<32, 256, 0, stream>>>(meanp, attnp, gw, gb, gbuf);
    mgemm<2, 1, 0, 2, 0><<<dim3(4, 64), 256, 0, stream>>>(
        gbuf, combh, combl, wp_dw1, db1, nullptr, hdh, hdl, nullptr,
        384, 256, 12, nullptr, nullptr, nullptr, nullptr);
    mgemm<1, 0, 0, 0, 1><<<dim3(2, 64), 256, 0, stream>>>(
        nullptr, hdh, hdl, wp_det, nullptr, nullptr, nullptr, nullptr, nullptr,
        256, 128, 8, o80, o4, cls_b, reg_b);
}

// Round 5
// 1470.274 us; speedup vs baseline: 1.6181x; 1.4422x over previous
//
#include <hip/hip_runtime.h>
#include <math.h>

// ---------------------------------------------------------------------------
// AttentionRoutingDetector — R5: conv2 rewritten (scalar-pipe weights, no LDS).
// Router path numerics are BIT-IDENTICAL to R4 (verified): same fp32 FMA order
// ic0->ic->kh->kw, fp64 carry per 8-ic block, fp32-emulated sigmoid chain.
// conv2 R4 was LDS-BW bound (144 b128 weight reads / 2304 FMA per block-pass,
// 6.3M bank-conflict cycles). Now: weights via s_load (wave-uniform oc group),
// inputs via direct coalesced global loads (L1-resident), zero barriers.
// ---------------------------------------------------------------------------

#define B_ALL 32

typedef __attribute__((ext_vector_type(8))) short short8;
typedef __attribute__((ext_vector_type(4))) float f32x4;

__device__ __forceinline__ unsigned short f2bf(float x) {
    unsigned u = __float_as_uint(x);
    return (unsigned short)((u + 0x7FFFu + ((u >> 16) & 1u)) >> 16);
}
__device__ __forceinline__ float bf2f(unsigned short h) {
    return __uint_as_float(((unsigned)h) << 16);
}
__device__ __forceinline__ unsigned pk(unsigned short a, unsigned short b) {
    return (unsigned)a | ((unsigned)b << 16);
}

// ---------------- conv1: (b,3,512,512) -> relu -> (b,64,256,256), stride 2
__global__ __launch_bounds__(256) void conv1_kernel(
    const float* __restrict__ img, const float* __restrict__ w,
    const float* __restrict__ bias, float* __restrict__ x1, int b0)
{
    const int ow = threadIdx.x;
    const int oh = blockIdx.x;
    const int bl = blockIdx.y;
    const int b  = b0 + bl;

    const float* ib = img + (size_t)b * 3 * 512 * 512;
    float in[3][3][3];
#pragma unroll
    for (int c = 0; c < 3; c++)
#pragma unroll
        for (int kh = 0; kh < 3; kh++) {
            int ih = oh * 2 + kh;
#pragma unroll
            for (int kw = 0; kw < 3; kw++) {
                int iw = ow * 2 + kw;
                in[c][kh][kw] = (ih < 512 && iw < 512)
                    ? ib[((size_t)c * 512 + ih) * 512 + iw] : 0.f;
            }
        }

    float* ob = x1 + ((size_t)bl * 64 * 256 + oh) * 256 + ow;
#pragma unroll 2
    for (int oc = 0; oc < 64; oc++) {
        const float* wp = w + oc * 27;
        float p[3] = {0.f, 0.f, 0.f};
#pragma unroll
        for (int c = 0; c < 3; c++)
#pragma unroll
            for (int kh = 0; kh < 3; kh++)
#pragma unroll
                for (int kw = 0; kw < 3; kw++)
                    p[c] = fmaf(in[c][kh][kw], wp[(c * 3 + kh) * 3 + kw], p[c]);
        double s = (double)bias[oc] + ((double)p[0] + (double)p[1] + (double)p[2]);
        float r = (float)s;
        ob[(size_t)oc * 256 * 256] = r > 0.f ? r : 0.f;
    }
}

// ---------------- conv2 weight transpose: w[oc][ic][kh][kw] -> wt[ic][kh][kw][oc]
__global__ __launch_bounds__(256) void wprep_conv2(
    const float* __restrict__ w, float* __restrict__ wt)
{
    int idx = blockIdx.x * 256 + threadIdx.x;
    if (idx >= 64 * 9 * 64) return;
    int oc = idx & 63;
    int r  = idx >> 6;          // ic*9 + kh*3 + kw
    wt[r * 64 + oc] = w[(size_t)oc * 576 + r];
}

// ---------------- conv2 + fused 8x8 pool partials (no LDS, no barriers).
// 256 thr = 4 waves; wave w -> oc 16w..16w+15 (weights wave-uniform -> s_load);
// lane -> 2 adjacent ow. fp32 FMA ic0->ic->kh->kw, fp64 carry per 8-ic block
// (bit-identical accumulation to R4). Writes tokd partials [bl][oc][oh][j].
__global__ __launch_bounds__(256, 3) void conv2_kernel(
    const float* __restrict__ x1, const float* __restrict__ wt,
    const float* __restrict__ bias, double* __restrict__ tokd)
{
    const int tid  = threadIdx.x;
    const int lane = tid & 63;
    const int wave = __builtin_amdgcn_readfirstlane(tid >> 6);   // 0..3, scalar
    const int oh   = blockIdx.x;          // 0..127
    const int bl   = blockIdx.y;
    const int ow0  = lane * 2;            // this thread: ow0, ow0+1

    const float* xb = x1 + (size_t)bl * 64 * 256 * 256;

    float  acc[2][16];
    double accd[2][16];
#pragma unroll
    for (int j = 0; j < 2; j++)
#pragma unroll
        for (int o = 0; o < 16; o++) { acc[j][o] = 0.f; accd[j][o] = 0.0; }

    for (int ic0 = 0; ic0 < 64; ic0 += 8) {
#pragma unroll 2
        for (int ic = 0; ic < 8; ic++) {
            const int icg = ic0 + ic;
#pragma unroll
            for (int kh = 0; kh < 3; kh++) {
                const int ih = oh * 2 + kh;
                if (ih < 256) {
                    const float* rp = xb + ((size_t)icg * 256 + ih) * 256 + ow0 * 2;
                    float4 f4 = *(const float4*)rp;            // cols 4L..4L+3
                    float  f5 = (ow0 < 126) ? rp[4] : 0.f;     // col 4L+4 (lane63 OOB=0)
                    // iw = 2*ow + kw : ow0 -> f4.x/f4.y/f4.z ; ow0+1 -> f4.z/f4.w/f5
                    float iv[3][2] = {{f4.x, f4.z}, {f4.y, f4.w}, {f4.z, f5}};
                    const float* wrow = wt + (size_t)((icg * 3 + kh) * 3) * 64 + wave * 16;
#pragma unroll
                    for (int kw = 0; kw < 3; kw++) {
                        const float* wp = wrow + kw * 64;       // uniform -> s_load
#pragma unroll
                        for (int o = 0; o < 16; o++) {
                            float wv = wp[o];
                            acc[0][o] = fmaf(iv[kw][0], wv, acc[0][o]);
                            acc[1][o] = fmaf(iv[kw][1], wv, acc[1][o]);
                        }
                    }
                }
            }
        }
        // carry this 72-term fp32 partial into fp64 (same cadence as R4)
#pragma unroll
        for (int j = 0; j < 2; j++)
#pragma unroll
            for (int o = 0; o < 16; o++) {
                accd[j][o] += (double)acc[j][o];
                acc[j][o] = 0.f;
            }
    }

    // bias + relu (fp32-rounded) then pool partial: sum 8 consecutive ow.
    // lanes 4j..4j+3 hold ow 8j..8j+7; xor-reduce, lane 4j writes col j.
#pragma unroll
    for (int o = 0; o < 16; o++) {
        const int oc = wave * 16 + o;
        const double bv = (double)bias[oc];
        double s = (double)fmaxf((float)(accd[0][o] + bv), 0.f)
                 + (double)fmaxf((float)(accd[1][o] + bv), 0.f);
        s += __shfl_xor(s, 1);
        s += __shfl_xor(s, 2);
        if ((lane & 3) == 0)
            tokd[(((size_t)bl * 64 + oc) * 128 + oh) * 16 + (lane >> 2)] = s;
    }
}

// ---------------- attention MLP from pooled tokens (fp64) + fp32-emulated
// sigmoid chain (identical to R3's verified decision rule).
__global__ __launch_bounds__(64) void attn_kernel(
    const double* __restrict__ tokd, const float* __restrict__ aw1,
    const float* __restrict__ ab1, const float* __restrict__ aw2,
    const float* __restrict__ ab2, const float* __restrict__ thrp,
    float* __restrict__ scores, float* __restrict__ maskf, int b0)
{
    const int c  = threadIdx.x;
    const int n  = blockIdx.x;
    const int bl = blockIdx.y;
    const int i = n >> 4, j = n & 15;

    const double* tp = tokd + (((size_t)bl * 64 + c) * 128 + i * 8) * 16 + j;
    double s = 0.0;
#pragma unroll
    for (int p = 0; p < 8; p++) s += tp[p * 16];

    __shared__ double tok[64];
    __shared__ double h[32];
    tok[c] = s * (1.0 / 64.0);
    __syncthreads();
    if (c < 32) {
        double acc = (double)ab1[c];
        for (int k = 0; k < 64; k++) acc += tok[k] * (double)aw1[k * 32 + c];
        h[c] = acc > 0.0 ? acc : 0.0;
    }
    __syncthreads();
    if (c == 0) {
        double logit = (double)ab2[0];
        for (int k = 0; k < 32; k++) logit += h[k] * (double)aw2[k];
        float lf = (float)logit;
        float e1 = (float)exp(-(double)lf);
        float d1 = 1.0f + e1;
        float sc = (float)(1.0 / (double)d1);
        float t  = sc - thrp[0];
        float e2 = (float)exp(-(double)t);
        float d2 = 1.0f + e2;
        float soft = (float)(1.0 / (double)d2);
        scores[(size_t)(b0 + bl) * 256 + n] = sc;
        maskf[(size_t)(b0 + bl) * 256 + n] = (soft > 0.5f) ? 1.f : 0.f;
    }
}

// ---------------- per-batch score sum
__global__ __launch_bounds__(256) void wsum_kernel(
    const float* __restrict__ scores, float* __restrict__ wsum)
{
    int b = blockIdx.x, t = threadIdx.x;
    float v = scores[b * 256 + t];
#pragma unroll
    for (int o = 32; o > 0; o >>= 1) v += __shfl_down(v, o);
    __shared__ float ls[4];
    if ((t & 63) == 0) ls[t >> 6] = v;
    __syncthreads();
    if (t == 0) wsum[b] = (ls[0] + ls[1] + ls[2] + ls[3]) + 1e-6f;
}

// ---------------- weight prep: pack W (KxN fp32) into MFMA fragment layout,
// split bf16 hi/lo: Wp[nt][kt][sub][h][lane][8]
__global__ __launch_bounds__(256) void wprep(
    const float* __restrict__ W, unsigned short* __restrict__ Wp, int K, int N, int Npad)
{
    int idx = blockIdx.x * 256 + threadIdx.x;
    int KT = K >> 5;
    int total = (Npad >> 6) * KT * 4 * 64;
    if (idx >= total) return;
    int lane = idx & 63;
    int sub  = (idx >> 6) & 3;
    int t    = idx >> 8;
    int kt = t % KT, nt = t / KT;
    int n  = nt * 64 + sub * 16 + (lane & 15);
    int k0 = kt * 32 + (lane >> 4) * 8;
    unsigned hw[4], lw[4];
#pragma unroll
    for (int q = 0; q < 4; q++) {
        float x0 = (n < N) ? W[(size_t)(k0 + 2 * q) * N + n] : 0.f;
        float x1 = (n < N) ? W[(size_t)(k0 + 2 * q + 1) * N + n] : 0.f;
        unsigned short h0 = f2bf(x0), h1 = f2bf(x1);
        hw[q] = pk(h0, h1);
        lw[q] = pk(f2bf(x0 - bf2f(h0)), f2bf(x1 - bf2f(h1)));
    }
    size_t base = ((((size_t)(nt * KT + kt) * 4 + sub) * 2) * 64 + lane) * 8;
    *(uint4*)(Wp + base)       = make_uint4(hw[0], hw[1], hw[2], hw[3]);
    *(uint4*)(Wp + base + 512) = make_uint4(lw[0], lw[1], lw[2], lw[3]);
}

// det head weights: concat cls_w (256x80) | reg_w (256x4), pad to 128 cols
__global__ __launch_bounds__(256) void wprep_det(
    const float* __restrict__ Wc, const float* __restrict__ Wr,
    unsigned short* __restrict__ Wp)
{
    int idx = blockIdx.x * 256 + threadIdx.x;
    const int KT = 8;
    int total = 2 * KT * 4 * 64;
    if (idx >= total) return;
    int lane = idx & 63;
    int sub  = (idx >> 6) & 3;
    int t    = idx >> 8;
    int kt = t % KT, nt = t / KT;
    int n  = nt * 64 + sub * 16 + (lane & 15);
    int k0 = kt * 32 + (lane >> 4) * 8;
    unsigned hw[4], lw[4];
#pragma unroll
    for (int q = 0; q < 4; q++) {
        int ka = k0 + 2 * q, kb = k0 + 2 * q + 1;
        float x0 = (n < 80) ? Wc[(size_t)ka * 80 + n] : (n < 84 ? Wr[(size_t)ka * 4 + n - 80] : 0.f);
        float x1 = (n < 80) ? Wc[(size_t)kb * 80 + n] : (n < 84 ? Wr[(size_t)kb * 4 + n - 80] : 0.f);
        unsigned short h0 = f2bf(x0), h1 = f2bf(x1);
        hw[q] = pk(h0, h1);
        lw[q] = pk(f2bf(x0 - bf2f(h0)), f2bf(x1 - bf2f(h1)));
    }
    size_t base = ((((size_t)(nt * KT + kt) * 4 + sub) * 2) * 64 + lane) * 8;
    *(uint4*)(Wp + base)       = make_uint4(hw[0], hw[1], hw[2], hw[3]);
    *(uint4*)(Wp + base + 512) = make_uint4(lw[0], lw[1], lw[2], lw[3]);
}

// ---------------- split-bf16 MFMA GEMM: C = epi(A @ W + bias)
// Tile 128(M) x 64(N) x 32(K); 4 waves, each 32 rows x 64 cols (8 C-tiles).
// ASRC: 0 = fp32 A (convert in staging); 1 = pre-split A (Ahg/Alg bf16);
//       2 = concat: kt<8 -> g fp32 (row m>>8, width 256); kt>=8 -> comb split (width 128)
// ACT: 1 = relu. MASK: 0 none / 1 keep(mask==1) / 2 keep(mask==0).
// OUTF: bit0 fp32 C, bit1 split Ch/Cl. EPID: 1 = detection dual-store (N=128 padded, real 84).
template <int ASRC, int ACT, int MASK, int OUTF, int EPID>
__global__ __launch_bounds__(256) void mgemm(
    const float* __restrict__ Af, const unsigned short* __restrict__ Ahg,
    const unsigned short* __restrict__ Alg, const unsigned short* __restrict__ Wp,
    const float* __restrict__ bias, float* __restrict__ Cf,
    unsigned short* __restrict__ Ch, unsigned short* __restrict__ Cl,
    const float* __restrict__ maskf, int K, int N, int KT,
    float* __restrict__ o80, float* __restrict__ o4,
    const float* __restrict__ clsb, const float* __restrict__ regb)
{
    __shared__ unsigned short AhL[128 * 40];
    __shared__ unsigned short AlL[128 * 40];

    const int tid  = threadIdx.x;
    const int wave = tid >> 6, lane = tid & 63;
    const int quad = lane >> 4, l16 = lane & 15;
    const int m0   = blockIdx.y * 128;
    const int srow = tid >> 1, shalf = tid & 1;

    f32x4 acc[2][4];
#pragma unroll
    for (int a = 0; a < 2; a++)
#pragma unroll
        for (int b = 0; b < 4; b++) acc[a][b] = (f32x4){0.f, 0.f, 0.f, 0.f};

    const unsigned short* wb = Wp + ((size_t)blockIdx.x * KT * 4 * 2 * 64 + lane) * 8;

    for (int kt = 0; kt < KT; kt++) {
        // ---- stage A tile (128 x 32)
        {
            const int m  = m0 + srow;
            const int kb = kt * 32 + shalf * 16;
            const int lofs = srow * 40 + shalf * 16;
            bool conv_path;
            if (ASRC == 0) conv_path = true;
            else if (ASRC == 1) conv_path = false;
            else conv_path = (kt < 8);

            if (conv_path) {
                const float* ap = (ASRC == 2) ? (Af + (size_t)(m >> 8) * 256 + kb)
                                              : (Af + (size_t)m * K + kb);
                float4 x0 = *(const float4*)(ap + 0);
                float4 x1 = *(const float4*)(ap + 4);
                float4 x2 = *(const float4*)(ap + 8);
                float4 x3 = *(const float4*)(ap + 12);
                float xv[16] = {x0.x, x0.y, x0.z, x0.w, x1.x, x1.y, x1.z, x1.w,
                                x2.x, x2.y, x2.z, x2.w, x3.x, x3.y, x3.z, x3.w};
                unsigned hw[8], lw[8];
#pragma unroll
                for (int q = 0; q < 8; q++) {
                    unsigned short h0 = f2bf(xv[2 * q]), h1 = f2bf(xv[2 * q + 1]);
                    unsigned short l0 = f2bf(xv[2 * q] - bf2f(h0));
                    unsigned short l1 = f2bf(xv[2 * q + 1] - bf2f(h1));
                    hw[q] = pk(h0, h1);
                    lw[q] = pk(l0, l1);
                }
                *(uint4*)&AhL[lofs]     = make_uint4(hw[0], hw[1], hw[2], hw[3]);
                *(uint4*)&AhL[lofs + 8] = make_uint4(hw[4], hw[5], hw[6], hw[7]);
                *(uint4*)&AlL[lofs]     = make_uint4(lw[0], lw[1], lw[2], lw[3]);
                *(uint4*)&AlL[lofs + 8] = make_uint4(lw[4], lw[5], lw[6], lw[7]);
            } else {
                const size_t ro = (ASRC == 2) ? ((size_t)m * 128 + (kb - 256))
                                              : ((size_t)m * K + kb);
                uint4 h0 = *(const uint4*)(Ahg + ro);
                uint4 h1 = *(const uint4*)(Ahg + ro + 8);
                uint4 l0 = *(const uint4*)(Alg + ro);
                uint4 l1 = *(const uint4*)(Alg + ro + 8);
                *(uint4*)&AhL[lofs]     = h0;
                *(uint4*)&AhL[lofs + 8] = h1;
                *(uint4*)&AlL[lofs]     = l0;
                *(uint4*)&AlL[lofs + 8] = l1;
            }
        }
        __syncthreads();

        const unsigned short* wk = wb + (size_t)kt * (4 * 2 * 64 * 8);
        short8 wh[4], wl[4];
#pragma unroll
        for (int s = 0; s < 4; s++) {
            wh[s] = *(const short8*)(wk + (size_t)s * (2 * 64 * 8));
            wl[s] = *(const short8*)(wk + (size_t)s * (2 * 64 * 8) + 64 * 8);
        }
        short8 ah[2], al[2];
#pragma unroll
        for (int mt = 0; mt < 2; mt++) {
            const int r = wave * 32 + mt * 16 + l16;
            ah[mt] = *(const short8*)&AhL[r * 40 + quad * 8];
            al[mt] = *(const short8*)&AlL[r * 40 + quad * 8];
        }
#pragma unroll
        for (int mt = 0; mt < 2; mt++)
#pragma unroll
            for (int s = 0; s < 4; s++) {
                acc[mt][s] = __builtin_amdgcn_mfma_f32_16x16x32_bf16(ah[mt], wh[s], acc[mt][s], 0, 0, 0);
                acc[mt][s] = __builtin_amdgcn_mfma_f32_16x16x32_bf16(al[mt], wh[s], acc[mt][s], 0, 0, 0);
                acc[mt][s] = __builtin_amdgcn_mfma_f32_16x16x32_bf16(ah[mt], wl[s], acc[mt][s], 0, 0, 0);
            }
        __syncthreads();
    }

    // ---- epilogue
    const int nbase = blockIdx.x * 64;
#pragma unroll
    for (int mt = 0; mt < 2; mt++) {
        const int mrow0 = m0 + wave * 32 + mt * 16 + quad * 4;
        float mk[4];
        if (MASK != 0) {
#pragma unroll
            for (int r = 0; r < 4; r++) mk[r] = maskf[mrow0 + r];
        }
#pragma unroll
        for (int s = 0; s < 4; s++) {
            const int n = nbase + s * 16 + l16;
            float bv;
            if (EPID == 1)
                bv = (n < 80) ? clsb[n] : (n < 84 ? regb[n - 80] : 0.f);
            else
                bv = bias[n];
#pragma unroll
            for (int r = 0; r < 4; r++) {
                const int m = mrow0 + r;
                float v = acc[mt][s][r] + bv;
                if (ACT) v = fmaxf(v, 0.f);
                bool st = true;
                if (MASK == 1) st = mk[r] > 0.5f;
                if (MASK == 2) st = mk[r] < 0.5f;
                if (st) {
                    if (OUTF & 1) Cf[(size_t)m * N + n] = v;
                    if (OUTF & 2) {
                        unsigned short hh = f2bf(v);
                        Ch[(size_t)m * N + n] = hh;
                        Cl[(size_t)m * N + n] = f2bf(v - bf2f(hh));
                    }
                    if (EPID == 1) {
                        if (n < 80)      o80[(size_t)m * 80 + n] = v;
                        else if (n < 84) o4[(size_t)m * 4 + (n - 80)] = v;
                    }
                }
            }
        }
    }
}

// ---------------- per-batch pooling of comb: mean & score-weighted
__global__ __launch_bounds__(128) void pool2_kernel(
    const float* __restrict__ comb, const float* __restrict__ scores,
    const float* __restrict__ wsum, float* __restrict__ meanp,
    float* __restrict__ attnp)
{
    int b = blockIdx.x, d = threadIdx.x;
    float ms = 0.f, as = 0.f;
    for (int n = 0; n < 256; n++) {
        float v = comb[((size_t)b * 256 + n) * 128 + d];
        ms += v;
        as = fmaf(scores[b * 256 + n], v, as);
    }
    meanp[b * 128 + d] = ms * (1.f / 256.f);
    attnp[b * 128 + d] = as / wsum[b];
}

// ---------------- aggregator
__global__ __launch_bounds__(256) void agg_kernel(
    const float* __restrict__ meanp, const float* __restrict__ attnp,
    const float* __restrict__ gw, const float* __restrict__ gb,
    float* __restrict__ g)
{
    int b = blockIdx.x, j = threadIdx.x;
    __shared__ float cat[256];
    cat[j] = (j < 128) ? meanp[b * 128 + j] : attnp[b * 128 + j - 128];
    __syncthreads();
    float acc = gb[j];
    for (int k = 0; k < 256; k++) acc = fmaf(cat[k], gw[k * 256 + j], acc);
    g[b * 256 + j] = acc > 0.f ? acc : 0.f;
}

// ---------------------------------------------------------------------------
extern "C" void kernel_launch(void* const* d_in, const int* in_sizes, int n_in,
                              void* d_out, int out_size, void* d_ws, size_t ws_size,
                              hipStream_t stream)
{
    (void)in_sizes; (void)n_in; (void)out_size;

    const float* images = (const float*)d_in[0];
    const float* patches = (const float*)d_in[1];
    const float* cw1 = (const float*)d_in[2];
    const float* cb1 = (const float*)d_in[3];
    const float* cw2 = (const float*)d_in[4];
    const float* cb2 = (const float*)d_in[5];
    const float* aw1 = (const float*)d_in[6];
    const float* ab1 = (const float*)d_in[7];
    const float* aw2 = (const float*)d_in[8];
    const float* ab2 = (const float*)d_in[9];
    const float* thr = (const float*)d_in[10];
    const float* bw1 = (const float*)d_in[11];
    const float* bb1 = (const float*)d_in[12];
    const float* bw2 = (const float*)d_in[13];
    const float* bb2 = (const float*)d_in[14];
    const float* bw3 = (const float*)d_in[15];
    const float* bb3 = (const float*)d_in[16];
    const float* bw4 = (const float*)d_in[17];
    const float* bb4 = (const float*)d_in[18];
    const float* sw1 = (const float*)d_in[19];
    const float* sb1 = (const float*)d_in[20];
    const float* sw2 = (const float*)d_in[21];
    const float* sb2 = (const float*)d_in[22];
    const float* gw  = (const float*)d_in[23];
    const float* gb  = (const float*)d_in[24];
    const float* dw1 = (const float*)d_in[25];
    const float* db1 = (const float*)d_in[26];
    const float* cls_w = (const float*)d_in[27];
    const float* cls_b = (const float*)d_in[28];
    const float* reg_w = (const float*)d_in[29];
    const float* reg_b = (const float*)d_in[30];
    float* out = (float*)d_out;
    float* o80 = out;
    float* o4  = out + 655360;

    // ---- workspace carve-up (bytes, 256-aligned)
    unsigned char* base = (unsigned char*)d_ws;
    size_t off = 0;
    auto alloc = [&](size_t bytes) -> unsigned char* {
        unsigned char* r = base + off;
        off += (bytes + 255) & ~(size_t)255;
        return r;
    };

    // fixed-size buffers first
    float*  scores = (float*)alloc(8192 * 4);
    float*  maskf  = (float*)alloc(8192 * 4);
    float*  wsumb  = (float*)alloc(32 * 4);
    float*  combf  = (float*)alloc((size_t)8192 * 128 * 4);
    float*  meanp  = (float*)alloc(4096 * 4);
    float*  attnp  = (float*)alloc(4096 * 4);
    float*  gbuf   = (float*)alloc(8192 * 4);
    float*  wtc2   = (float*)alloc((size_t)64 * 9 * 64 * 4);   // conv2 transposed weights

    typedef unsigned short ush;
    ush* wp_bw1 = (ush*)alloc((size_t)8 * 96 * 4096 * 2);
    ush* wp_bw2 = (ush*)alloc((size_t)8 * 16 * 4096 * 2);
    ush* wp_bw3 = (ush*)alloc((size_t)8 * 16 * 4096 * 2);
    ush* wp_bw4 = (ush*)alloc((size_t)2 * 16 * 4096 * 2);
    ush* wp_sw1 = (ush*)alloc((size_t)1 * 96 * 4096 * 2);
    ush* wp_sw2 = (ush*)alloc((size_t)2 * 2 * 4096 * 2);
    ush* wp_dw1 = (ush*)alloc((size_t)4 * 12 * 4096 * 2);
    ush* wp_det = (ush*)alloc((size_t)2 * 8 * 4096 * 2);

    ush* hb1h = (ush*)alloc((size_t)8192 * 512 * 2);
    ush* hb1l = (ush*)alloc((size_t)8192 * 512 * 2);
    ush* hb2h = (ush*)alloc((size_t)8192 * 512 * 2);
    ush* hb2l = (ush*)alloc((size_t)8192 * 512 * 2);
    ush* hb3h = (ush*)alloc((size_t)8192 * 512 * 2);
    ush* hb3l = (ush*)alloc((size_t)8192 * 512 * 2);
    ush* hsh  = (ush*)alloc((size_t)8192 * 64 * 2);
    ush* hsl  = (ush*)alloc((size_t)8192 * 64 * 2);
    ush* combh = (ush*)alloc((size_t)8192 * 128 * 2);
    ush* combl = (ush*)alloc((size_t)8192 * 128 * 2);
    ush* hdh  = (ush*)alloc((size_t)8192 * 256 * 2);
    ush* hdl  = (ush*)alloc((size_t)8192 * 256 * 2);

    // slice-sized buffers: x1 + tokd
    size_t remain = (ws_size > off) ? (ws_size - off) : 0;
    int SL = 8;
    while (SL > 1) {
        size_t need = (size_t)SL * 64 * 256 * 256 * 4 + (size_t)SL * 64 * 128 * 16 * 8 + 1024;
        if (need <= remain) break;
        SL >>= 1;
    }
    float*  x1   = (float*)alloc((size_t)SL * 64 * 256 * 256 * 4);
    double* tokd = (double*)alloc((size_t)SL * 64 * 128 * 16 * 8);

    // ---- weight preps
    {
        wprep_conv2<<<(64 * 9 * 64 + 255) / 256, 256, 0, stream>>>(cw2, wtc2);
        int t1 = 8 * 96 * 4 * 64;  wprep<<<(t1 + 255) / 256, 256, 0, stream>>>(bw1, wp_bw1, 3072, 512, 512);
        int t2 = 8 * 16 * 4 * 64;  wprep<<<(t2 + 255) / 256, 256, 0, stream>>>(bw2, wp_bw2, 512, 512, 512);
                                   wprep<<<(t2 + 255) / 256, 256, 0, stream>>>(bw3, wp_bw3, 512, 512, 512);
        int t4 = 2 * 16 * 4 * 64;  wprep<<<(t4 + 255) / 256, 256, 0, stream>>>(bw4, wp_bw4, 512, 128, 128);
        int t5 = 1 * 96 * 4 * 64;  wprep<<<(t5 + 255) / 256, 256, 0, stream>>>(sw1, wp_sw1, 3072, 64, 64);
        int t6 = 2 * 2 * 4 * 64;   wprep<<<(t6 + 255) / 256, 256, 0, stream>>>(sw2, wp_sw2, 64, 128, 128);
        int t7 = 4 * 12 * 4 * 64;  wprep<<<(t7 + 255) / 256, 256, 0, stream>>>(dw1, wp_dw1, 384, 256, 256);
        int t8 = 2 * 8 * 4 * 64;   wprep_det<<<(t8 + 255) / 256, 256, 0, stream>>>(cls_w, reg_w, wp_det);
    }

    // ---- backbone + attention scores, batch-sliced
    for (int s = 0; s < B_ALL / SL; s++) {
        conv1_kernel<<<dim3(256, SL), 256, 0, stream>>>(images, cw1, cb1, x1, s * SL);
        conv2_kernel<<<dim3(128, SL), 256, 0, stream>>>(x1, wtc2, cb2, tokd);
        attn_kernel<<<dim3(256, SL), 64, 0, stream>>>(tokd, aw1, ab1, aw2, ab2,
                                                      thr, scores, maskf, s * SL);
    }
    wsum_kernel<<<32, 256, 0, stream>>>(scores, wsumb);

    // ---- experts (split-bf16 MFMA)
    mgemm<0, 1, 0, 2, 0><<<dim3(8, 64), 256, 0, stream>>>(
        patches, nullptr, nullptr, wp_bw1, bb1, nullptr, hb1h, hb1l, nullptr,
        3072, 512, 96, nullptr, nullptr, nullptr, nullptr);
    mgemm<1, 1, 0, 2, 0><<<dim3(8, 64), 256, 0, stream>>>(
        nullptr, hb1h, hb1l, wp_bw2, bb2, nullptr, hb2h, hb2l, nullptr,
        512, 512, 16, nullptr, nullptr, nullptr, nullptr);
    mgemm<1, 1, 0, 2, 0><<<dim3(8, 64), 256, 0, stream>>>(
        nullptr, hb2h, hb2l, wp_bw3, bb3, nullptr, hb3h, hb3l, nullptr,
        512, 512, 16, nullptr, nullptr, nullptr, nullptr);
    mgemm<1, 0, 1, 3, 0><<<dim3(2, 64), 256, 0, stream>>>(
        nullptr, hb3h, hb3l, wp_bw4, bb4, combf, combh, combl, maskf,
        512, 128, 16, nullptr, nullptr, nullptr, nullptr);
    mgemm<0, 1, 0, 2, 0><<<dim3(1, 64), 256, 0, stream>>>(
        patches, nullptr, nullptr, wp_sw1, sb1, nullptr, hsh, hsl, nullptr,
        3072, 64, 96, nullptr, nullptr, nullptr, nullptr);
    mgemm<1, 0, 2, 3, 0><<<dim3(2, 64), 256, 0, stream>>>(
        nullptr, hsh, hsl, wp_sw2, sb2, combf, combh, combl, maskf,
        64, 128, 2, nullptr, nullptr, nullptr, nullptr);

    // ---- aggregate + detection
    pool2_kernel<<<32, 128, 0, stream>>>(combf, scores, wsumb, meanp, attnp);
    agg_kernel<<<32, 256, 0, stream>>>(meanp, attnp, gw, gb, gbuf);
    mgemm<2, 1, 0, 2, 0><<<dim3(4, 64), 256, 0, stream>>>(
        gbuf, combh, combl, wp_dw1, db1, nullptr, hdh, hdl, nullptr,
        384, 256, 12, nullptr, nullptr, nullptr, nullptr);
    mgemm<1, 0, 0, 0, 1><<<dim3(2, 64), 256, 0, stream>>>(
        nullptr, hdh, hdl, wp_det, nullptr, nullptr, nullptr, nullptr, nullptr,
        256, 128, 8, o80, o4, cls_b, reg_b);
}